// Round 9
// baseline (407.660 us; speedup 1.0000x reference)
//
#include <hip/hip_runtime.h>
#include <stdint.h>

#define DM   768
#define HEADS 12
#define DK    64
#define SEQ  2048
#define BATCH  4

typedef __bf16 bf16_t;
typedef __bf16 bf16x8 __attribute__((ext_vector_type(8)));
typedef __bf16 bf16x4 __attribute__((ext_vector_type(4)));
typedef float  f32x4  __attribute__((ext_vector_type(4)));
typedef float  f32x16 __attribute__((ext_vector_type(16)));
typedef unsigned u32x4 __attribute__((ext_vector_type(4)));

#define LOG2E 1.44269504f
#define MASKVAL (-1.442695e9f)
#define DEFER_THR 8.0f

// ---- workspace layout (bytes), all 256-aligned ----
#define OFF_FLAG 0
#define OFF_MASK 256
#define SZ_MASK  (BATCH*SEQ*(SEQ/32)*4)          // 2 MB packed mask bits
#define OFF_WT   (OFF_MASK + SZ_MASK)
#define SZ_WT1   (DM*DM*2)                       // one bf16 weight (transposed)
#define OFF_XB   (OFF_WT + 4*SZ_WT1)             // bf16 Q,K,V inputs (3 x 12.6MB)
#define SZ_X     (BATCH*SEQ*DM*2)
#define OFF_QP   (OFF_XB + 3*SZ_X)
#define SZ_PROJ  (BATCH*HEADS*SEQ*DK*2)          // 12.6 MB
#define OFF_KP   (OFF_QP + SZ_PROJ)
#define OFF_VT   (OFF_KP + SZ_PROJ)
#define OFF_ML   (OFF_VT + SZ_PROJ)              // 2 x [B][H][S] x {m,l} f32
#define SZ_ML    (2*BATCH*HEADS*SEQ*2*4)
// OP (split-kv partial O, bf16, 2 x [B][H][S][DK]) aliases XB slots 1,2 (dead after proj)
// CTX aliases XB slot 0 (dead after proj z=0)

__device__ __forceinline__ void gload_lds16(const bf16_t* g, bf16_t* l) {
    __builtin_amdgcn_global_load_lds((const __attribute__((address_space(1))) unsigned int*)g,
                                     (__attribute__((address_space(3))) unsigned int*)l, 16, 0, 0);
}

__device__ __forceinline__ unsigned pack2(float lo, float hi) {
    union { bf16_t b[2]; unsigned u; } x;
    x.b[0] = (bf16_t)lo; x.b[1] = (bf16_t)hi;
    return x.u;
}

// Pack mask (True => masked) into bits; mask element width detected in-kernel
// (uniform scalar check of first 64 words: int32 0/1 has bytes 1..3 zero).
__global__ void pack_mask_kernel(const unsigned int* __restrict__ mraw,
                                 unsigned int* __restrict__ words) {
    int is32 = 1;
    #pragma unroll
    for (int i = 0; i < 64; i++) is32 &= ((mraw[i] & 0xFFFFFF00u) == 0u);
    const unsigned int total = BATCH*SEQ*SEQ;
    const int* mi = (const int*)mraw;
    const unsigned char* mb = (const unsigned char*)mraw;
    unsigned int stride = gridDim.x * blockDim.x;
    unsigned int lane = threadIdx.x & 63u;
    for (unsigned int e = blockIdx.x * blockDim.x + threadIdx.x; e < total; e += stride) {
        int v = is32 ? (mi[e] != 0) : (mb[e] != 0);
        unsigned long long bal = __ballot(v);
        if ((lane & 31u) == 0u)
            words[e >> 5] = (unsigned int)(bal >> ((lane >> 5) * 32u));
    }
}

// Transpose + convert weights to bf16: W[k][n] f32 -> Wt[n][k] bf16
__global__ void wt_cvt_kernel(const float* __restrict__ W0, const float* __restrict__ W1,
                              const float* __restrict__ W2, const float* __restrict__ W3,
                              bf16_t* __restrict__ dst) {
    const float* W = blockIdx.z == 0 ? W0 : blockIdx.z == 1 ? W1 : blockIdx.z == 2 ? W2 : W3;
    bf16_t* out = dst + (size_t)blockIdx.z * DM * DM;
    __shared__ float tile[64][65];
    int w = threadIdx.x >> 6, u = threadIdx.x & 63;
    int kb = blockIdx.x * 64, nb = blockIdx.y * 64;
    #pragma unroll
    for (int i = 0; i < 16; i++)
        tile[w + 4*i][u] = W[(size_t)(kb + w + 4*i)*DM + nb + u];
    __syncthreads();
    #pragma unroll
    for (int i = 0; i < 16; i++)
        out[(size_t)(nb + w + 4*i)*DM + kb + u] = (bf16_t)tile[u][w + 4*i];
}

// Convert fp32 inputs to bf16
__global__ void xcvt_kernel(const float* __restrict__ Q, const float* __restrict__ K,
                            const float* __restrict__ V, bf16_t* __restrict__ XB) {
    int z = blockIdx.y;
    const float* src = z == 0 ? Q : z == 1 ? K : V;
    bf16_t* dst = XB + (size_t)z * BATCH*SEQ*DM;
    size_t i = ((size_t)blockIdx.x * blockDim.x + threadIdx.x) * 8;
    float4 a = *(const float4*)(src + i);
    float4 b = *(const float4*)(src + i + 4);
    bf16x8 o;
    o[0]=(bf16_t)a.x; o[1]=(bf16_t)a.y; o[2]=(bf16_t)a.z; o[3]=(bf16_t)a.w;
    o[4]=(bf16_t)b.x; o[5]=(bf16_t)b.y; o[6]=(bf16_t)b.z; o[7]=(bf16_t)b.w;
    *(bf16x8*)(dst + i) = o;
}

// 128x192 tile mainloop, 4 waves as 2m x 2n. smem = As(128x64) ++ Bs(192x64).
// Per wave per K-step: 20 ds_read_b128, 48 MFMA.
__device__ __forceinline__ void mm_mainloop192(const bf16_t* __restrict__ Aptr,
                                               const bf16_t* __restrict__ Bptr,
                                               bf16_t* smem,
                                               f32x4 acc[4][6], int bm, int bn) {
    bf16_t* As = smem;
    bf16_t* Bs = smem + 128*64;
    int tid = threadIdx.x, u = tid & 63, c = u & 15, g = u >> 4;
    int w = tid >> 6, wr = w & 1, wc = w >> 1;
    for (int k0 = 0; k0 < DM; k0 += 64) {
        #pragma unroll
        for (int i = 0; i < 4; i++) {
            int q = i*256 + tid;
            int row = q >> 3, col8 = q & 7;
            gload_lds16(Aptr + (size_t)(bm*128 + row)*DM + k0 + col8*8, As + q*8);
        }
        #pragma unroll
        for (int i = 0; i < 6; i++) {
            int q = i*256 + tid;
            int row = q >> 3, col8 = q & 7;
            gload_lds16(Bptr + (size_t)(bn*192 + row)*DM + k0 + col8*8, Bs + q*8);
        }
        __syncthreads();
        #pragma unroll
        for (int kk = 0; kk < 2; kk++) {
            bf16x8 a[4], bfr[6];
            #pragma unroll
            for (int mi = 0; mi < 4; mi++)
                a[mi] = *(const bf16x8*)(As + (wr*64 + mi*16 + c)*64 + kk*32 + g*8);
            #pragma unroll
            for (int ni = 0; ni < 6; ni++)
                bfr[ni] = *(const bf16x8*)(Bs + (wc*96 + ni*16 + c)*64 + kk*32 + g*8);
            #pragma unroll
            for (int mi = 0; mi < 4; mi++)
                #pragma unroll
                for (int ni = 0; ni < 6; ni++)
                    acc[mi][ni] = __builtin_amdgcn_mfma_f32_16x16x32_bf16(a[mi], bfr[ni], acc[mi][ni], 0, 0, 0);
        }
        __syncthreads();
    }
}

// XCD-chunked linear grid mapping: the 4 bn-blocks sharing one A-slab land on
// the same XCD (lin%8 == bm%8 fixed across bn) -> A slab stays in that L2.
__device__ __forceinline__ void grid_map(int lin, int& bm, int& bn) {
    bm = ((lin >> 5) << 3) | (lin & 7);
    bn = (lin >> 3) & 3;
}

// QKV projections: z=0 Q (scaled 0.125*log2e), z=1 K, z=2 V (transposed store,
// coalesced via LDS transpose epilogue)
__global__ __launch_bounds__(256) void proj192_kernel(
        const bf16_t* __restrict__ XB, const bf16_t* __restrict__ WT,
        const float* __restrict__ bQ, const float* __restrict__ bK, const float* __restrict__ bV,
        bf16_t* __restrict__ QP, bf16_t* __restrict__ KP, bf16_t* __restrict__ VT) {
    int z = blockIdx.y;
    const bf16_t* Aptr = XB + (size_t)z * BATCH*SEQ*DM;
    const bf16_t* Bptr = WT + (size_t)z * DM * DM;
    const float* bias = z == 0 ? bQ : z == 1 ? bK : bV;
    float scale = (z == 0) ? 0.125f * LOG2E : 1.0f;
    __shared__ __align__(16) bf16_t smem[128*64 + 192*64];
    int tid = threadIdx.x, u = tid & 63, c = u & 15, g = u >> 4;
    int w = tid >> 6, wr = w & 1, wc = w >> 1;
    int bm, bn; grid_map(blockIdx.x, bm, bn);
    f32x4 zero = {0.f,0.f,0.f,0.f};
    f32x4 acc[4][6] = {{zero,zero,zero,zero,zero,zero},{zero,zero,zero,zero,zero,zero},
                       {zero,zero,zero,zero,zero,zero},{zero,zero,zero,zero,zero,zero}};
    mm_mainloop192(Aptr, Bptr, smem, acc, bm, bn);
    if (z < 2) {
        bf16_t* dst = (z == 0) ? QP : KP;
        #pragma unroll
        for (int ni = 0; ni < 6; ni++) {
            int n = bn*192 + wc*96 + ni*16 + c;
            int h = n >> 6, d = n & 63;
            float bv = bias[n];
            #pragma unroll
            for (int mi = 0; mi < 4; mi++)
                #pragma unroll
                for (int j = 0; j < 4; j++) {
                    int r = bm*128 + wr*64 + mi*16 + 4*g + j;
                    int bidx = r >> 11, s = r & 2047;
                    dst[(((size_t)bidx*HEADS + h)*SEQ + s)*DK + d] = (bf16_t)((acc[mi][ni][j] + bv)*scale);
                }
        }
    } else {
        // V: transpose through LDS -> coalesced 16B stores into VT [b][h][d][s]
        #pragma unroll
        for (int p = 0; p < 2; p++) {
            if (wc == p) {
                #pragma unroll
                for (int ni = 0; ni < 6; ni++) {
                    int n = bn*192 + wc*96 + ni*16 + c;
                    float bv = bias[n];
                    #pragma unroll
                    for (int mi = 0; mi < 4; mi++)
                        #pragma unroll
                        for (int j = 0; j < 4; j++) {
                            int r_loc = wr*64 + mi*16 + 4*g + j;
                            smem[(ni*16 + c)*136 + r_loc] = (bf16_t)(acc[mi][ni][j] + bv);
                        }
                }
            }
            __syncthreads();
            #pragma unroll
            for (int it = 0; it < 6; it++) {
                int idx = it*256 + tid;
                int n_l = idx >> 4, r8 = (idx & 15) << 3;
                bf16x8 v = *(const bf16x8*)(smem + n_l*136 + r8);
                int n = bn*192 + p*96 + n_l;
                int h = n >> 6, d = n & 63;
                int r0 = bm*128 + r8;
                int bidx = r0 >> 11, s0 = r0 & 2047;
                *(bf16x8*)(VT + (((size_t)bidx*HEADS + h)*DK + d)*SEQ + s0) = v;
            }
            __syncthreads();
        }
    }
}

// Output projection: out = CTX @ Wfc + bfc + Q (fp32)
__global__ __launch_bounds__(256) void out192_kernel(
        const bf16_t* __restrict__ CTX, const bf16_t* __restrict__ WfcT,
        const float* __restrict__ bfc, const float* __restrict__ Qres, float* __restrict__ out) {
    __shared__ __align__(16) bf16_t smem[128*64 + 192*64];
    int tid = threadIdx.x, u = tid & 63, c = u & 15, g = u >> 4;
    int w = tid >> 6, wr = w & 1, wc = w >> 1;
    int bm, bn; grid_map(blockIdx.x, bm, bn);
    f32x4 zero = {0.f,0.f,0.f,0.f};
    f32x4 acc[4][6] = {{zero,zero,zero,zero,zero,zero},{zero,zero,zero,zero,zero,zero},
                       {zero,zero,zero,zero,zero,zero},{zero,zero,zero,zero,zero,zero}};
    mm_mainloop192(CTX, WfcT, smem, acc, bm, bn);
    #pragma unroll
    for (int ni = 0; ni < 6; ni++) {
        int n = bn*192 + wc*96 + ni*16 + c;
        float bv = bfc[n];
        #pragma unroll
        for (int mi = 0; mi < 4; mi++)
            #pragma unroll
            for (int j = 0; j < 4; j++) {
                int r = bm*128 + wr*64 + mi*16 + 4*g + j;
                out[(size_t)r*DM + n] = acc[mi][ni][j] + bv + Qres[(size_t)r*DM + n];
            }
    }
}

// ---------------- Flash attention, split-KV 2-way ----------------
// Block: 4 waves x 32 q-rows = 128 q, KV range = split*1024..+1024 (16 tiles).
// K/V double-buffered LDS (16B XOR swizzle); swapped QK^T with mask values fed
// as the MFMA C-operand; defer-max; pack+permlane P->bf16. Writes unnormalized
// O^T (bf16) + (m,l).
__global__ __launch_bounds__(256) void attn_kernel(
        const bf16_t* __restrict__ QP, const bf16_t* __restrict__ KP, const bf16_t* __restrict__ VT,
        const unsigned int* __restrict__ maskw, bf16_t* __restrict__ OP, float* __restrict__ ML) {
    __shared__ __align__(16) bf16_t kbuf[2][64*64];
    __shared__ __align__(16) bf16_t vbuf[2][64*64];
    __shared__ __align__(16) float lut4[64];
    int tid = threadIdx.x, w = tid >> 6, u = tid & 63;
    int qc = u & 31, hi = u >> 5;
    int sp = blockIdx.z & 1, b = blockIdx.z >> 1, h = blockIdx.y;
    int kvbase = sp << 10;
    int qg = blockIdx.x * 128 + w * 32 + qc;      // this lane's q row
    size_t bh = (size_t)(b * HEADS + h);
    const bf16_t* qp = QP + bh * SEQ * DK;
    const bf16_t* kp = KP + bh * SEQ * DK;
    const bf16_t* vt = VT + bh * DK * SEQ;
    const unsigned int* mwq = maskw + ((size_t)b * SEQ + qg) * (SEQ/32);

    // mask LUT: entry e (4 bits) -> 4 floats {0 or MASKVAL}
    if (tid < 64) lut4[tid] = (((tid >> 2) >> (tid & 3)) & 1) ? MASKVAL : 0.f;

    // persistent Q fragments (B-operand)
    bf16x8 qf[4];
    #pragma unroll
    for (int t = 0; t < 4; t++)
        qf[t] = *(const bf16x8*)(qp + (size_t)qg*DK + 16*t + 8*hi);

    int sr = tid >> 3, scc = tid & 7;

    f32x16 zz = {0,0,0,0,0,0,0,0,0,0,0,0,0,0,0,0};
    f32x16 acc0 = zz, acc1 = zz;
    float mrun = -16384.0f, lsum = 0.f;

    // prologue: stage tile 0 into buf 0
    #pragma unroll
    for (int i = 0; i < 2; i++) {
        int r = i*32 + sr;
        int gc = (scc ^ (r & 7)) << 3;
        gload_lds16(kp + (size_t)(kvbase + r)*DK + gc,   &kbuf[0][0] + i*2048 + tid*8);
        gload_lds16(vt + (size_t)r*SEQ + kvbase + gc,    &vbuf[0][0] + i*2048 + tid*8);
    }
    uint2 mv = *(const uint2*)(mwq + (kvbase >> 5));
    __syncthreads();

    for (int kt = 0; kt < 16; kt++) {
        int kb = kvbase + kt * 64;
        int cur = kt & 1;
        uint2 mv_next = mv;
        // prefetch next mask words + stage next K/V tile
        if (kt + 1 < 16) {
            mv_next = *(const uint2*)(mwq + ((kb + 64) >> 5));
            int nkb = kb + 64;
            #pragma unroll
            for (int i = 0; i < 2; i++) {
                int r = i*32 + sr;
                int gc = (scc ^ (r & 7)) << 3;
                gload_lds16(kp + (size_t)(nkb + r)*DK + gc, &kbuf[cur^1][0] + i*2048 + tid*8);
                gload_lds16(vt + (size_t)r*SEQ + nkb + gc,  &vbuf[cur^1][0] + i*2048 + tid*8);
            }
        }
        const bf16_t* kl = &kbuf[cur][0];
        const bf16_t* vl = &vbuf[cur][0];

        // mask add-values via LDS LUT -> fed directly as the MFMA C operand
        f32x16 s0, s1;
        #pragma unroll
        for (int j = 0; j < 4; j++) {
            f32x4 a0 = *(const f32x4*)&lut4[((mv.x >> (8*j + 4*hi)) & 0xFu) * 4];
            f32x4 a1 = *(const f32x4*)&lut4[((mv.y >> (8*j + 4*hi)) & 0xFu) * 4];
            #pragma unroll
            for (int i = 0; i < 4; i++) { s0[4*j + i] = a0[i]; s1[4*j + i] = a1[i]; }
        }

        // QK^T (S^T): 8 x mfma_32x32x16, accumulating onto the mask values
        __builtin_amdgcn_s_setprio(1);
        #pragma unroll
        for (int t = 0; t < 4; t++) {
            int col = (16*t + 8*hi);
            int r0 = qc, r1 = 32 + qc;
            bf16x8 k0 = *(const bf16x8*)(kl + r0*64 + (col ^ ((r0 & 7) << 3)));
            bf16x8 k1 = *(const bf16x8*)(kl + r1*64 + (col ^ ((r1 & 7) << 3)));
            s0 = __builtin_amdgcn_mfma_f32_32x32x16_bf16(k0, qf[t], s0, 0, 0, 0);
            s1 = __builtin_amdgcn_mfma_f32_32x32x16_bf16(k1, qf[t], s1, 0, 0, 0);
        }
        __builtin_amdgcn_s_setprio(0);

        // per-lane tile max, grouped 4-way for v_max3 fusion
        float q8[8];
        #pragma unroll
        for (int r = 0; r < 8; r++)
            q8[r] = fmaxf(fmaxf(s0[r], s0[r+8]), fmaxf(s1[r], s1[r+8]));
        float q4a = fmaxf(fmaxf(q8[0], q8[1]), fmaxf(q8[2], q8[3]));
        float q4b = fmaxf(fmaxf(q8[4], q8[5]), fmaxf(q8[6], q8[7]));
        float tm = fmaxf(q4a, q4b);

        // defer-max: rescale only if some row grew past mrun + THR
        if (!__all(tm <= mrun + DEFER_THR)) {
            float rmax = fmaxf(tm, __shfl_xor(tm, 32));
            float mn = fmaxf(mrun, rmax);
            float alpha = __builtin_amdgcn_exp2f(mrun - mn);
            mrun = mn;
            lsum *= alpha;
            acc0 *= alpha;
            acc1 *= alpha;
        }

        // exp2 (p bounded by 2^THR)
        #pragma unroll
        for (int r = 0; r < 16; r++) {
            s0[r] = __builtin_amdgcn_exp2f(s0[r] - mrun);
            s1[r] = __builtin_amdgcn_exp2f(s1[r] - mrun);
        }
        // sum
        f32x16 sv = s0 + s1;
        float a8[8];
        #pragma unroll
        for (int r = 0; r < 8; r++) a8[r] = sv[r] + sv[r+8];
        float a4a = (a8[0] + a8[1]) + (a8[2] + a8[3]);
        float a4b = (a8[4] + a8[5]) + (a8[6] + a8[7]);
        float rsum = a4a + a4b;
        lsum += rsum + __shfl_xor(rsum, 32);

        // P -> bf16 PA fragments via pack2 + permlane32_swap
        bf16x8 pa[4];
        {
            union { u32x4 uv; bf16x8 bv; } cv;
            unsigned x0, y0, x1, y1;
            x0 = pack2(s0[0], s0[1]); y0 = pack2(s0[4], s0[5]);
            asm volatile("v_permlane32_swap_b32 %0, %1" : "+v"(x0), "+v"(y0));
            x1 = pack2(s0[2], s0[3]); y1 = pack2(s0[6], s0[7]);
            asm volatile("v_permlane32_swap_b32 %0, %1" : "+v"(x1), "+v"(y1));
            cv.uv[0]=x0; cv.uv[1]=x1; cv.uv[2]=y0; cv.uv[3]=y1; pa[0]=cv.bv;
            x0 = pack2(s0[8], s0[9]);  y0 = pack2(s0[12], s0[13]);
            asm volatile("v_permlane32_swap_b32 %0, %1" : "+v"(x0), "+v"(y0));
            x1 = pack2(s0[10], s0[11]); y1 = pack2(s0[14], s0[15]);
            asm volatile("v_permlane32_swap_b32 %0, %1" : "+v"(x1), "+v"(y1));
            cv.uv[0]=x0; cv.uv[1]=x1; cv.uv[2]=y0; cv.uv[3]=y1; pa[1]=cv.bv;
            x0 = pack2(s1[0], s1[1]); y0 = pack2(s1[4], s1[5]);
            asm volatile("v_permlane32_swap_b32 %0, %1" : "+v"(x0), "+v"(y0));
            x1 = pack2(s1[2], s1[3]); y1 = pack2(s1[6], s1[7]);
            asm volatile("v_permlane32_swap_b32 %0, %1" : "+v"(x1), "+v"(y1));
            cv.uv[0]=x0; cv.uv[1]=x1; cv.uv[2]=y0; cv.uv[3]=y1; pa[2]=cv.bv;
            x0 = pack2(s1[8], s1[9]);  y0 = pack2(s1[12], s1[13]);
            asm volatile("v_permlane32_swap_b32 %0, %1" : "+v"(x0), "+v"(y0));
            x1 = pack2(s1[10], s1[11]); y1 = pack2(s1[14], s1[15]);
            asm volatile("v_permlane32_swap_b32 %0, %1" : "+v"(x1), "+v"(y1));
            cv.uv[0]=x0; cv.uv[1]=x1; cv.uv[2]=y0; cv.uv[3]=y1; pa[3]=cv.bv;
        }

        // PV: O^T += V^T . P^T
        __builtin_amdgcn_s_setprio(1);
        #pragma unroll
        for (int ks = 0; ks < 4; ks++) {
            int col = 16*ks + 8*hi;
            int r0 = qc, r1 = 32 + qc;
            bf16x8 v0 = *(const bf16x8*)(vl + r0*64 + (col ^ ((r0 & 7) << 3)));
            bf16x8 v1 = *(const bf16x8*)(vl + r1*64 + (col ^ ((r1 & 7) << 3)));
            acc0 = __builtin_amdgcn_mfma_f32_32x32x16_bf16(v0, pa[ks], acc0, 0, 0, 0);
            acc1 = __builtin_amdgcn_mfma_f32_32x32x16_bf16(v1, pa[ks], acc1, 0, 0, 0);
        }
        __builtin_amdgcn_s_setprio(0);

        __syncthreads();
        mv = mv_next;
    }

    // write unnormalized partial O^T (bf16) + (m,l)
    size_t prow = ((size_t)(sp * BATCH + b) * HEADS + h) * SEQ + qg;
    #pragma unroll
    for (int gr = 0; gr < 4; gr++) {
        bf16x4 o0, o1;
        #pragma unroll
        for (int jj = 0; jj < 4; jj++) {
            o0[jj] = (bf16_t)acc0[4*gr + jj];
            o1[jj] = (bf16_t)acc1[4*gr + jj];
        }
        *(bf16x4*)(OP + prow*DK + gr*8 + hi*4)      = o0;
        *(bf16x4*)(OP + prow*DK + 32 + gr*8 + hi*4) = o1;
    }
    if (hi == 0) {
        float2 ml = {mrun, lsum};
        *(float2*)(ML + prow*2) = ml;
    }
}

// Combine split-KV partials -> CTX (bf16)
__global__ __launch_bounds__(256) void attn_combine_kernel(
        const bf16_t* __restrict__ OP, const float* __restrict__ ML, bf16_t* __restrict__ CTX) {
    int tid = threadIdx.x;
    int r = tid >> 2, dc = (tid & 3) << 4;
    int h = blockIdx.y, b = blockIdx.z;
    int q = blockIdx.x * 64 + r;
    const size_t P = (size_t)BATCH * HEADS * SEQ;
    size_t row0 = ((size_t)b * HEADS + h) * SEQ + q;
    size_t row1 = row0 + P;
    float2 ml0 = *(const float2*)(ML + row0*2);
    float2 ml1 = *(const float2*)(ML + row1*2);
    float M = fmaxf(ml0.x, ml1.x);
    float w0 = exp2f(ml0.x - M), w1 = exp2f(ml1.x - M);
    float inv = 1.0f / (w0*ml0.y + w1*ml1.y);
    w0 *= inv; w1 *= inv;
    const bf16x8* pa = (const bf16x8*)(OP + row0*DK + dc);
    const bf16x8* pb = (const bf16x8*)(OP + row1*DK + dc);
    bf16_t* dst = CTX + ((size_t)b*SEQ + q)*DM + h*DK + dc;
    #pragma unroll
    for (int k = 0; k < 2; k++) {
        bf16x8 av = pa[k], bv = pb[k];
        bf16x8 o;
        #pragma unroll
        for (int i = 0; i < 8; i++)
            o[i] = (bf16_t)((float)av[i]*w0 + (float)bv[i]*w1);
        *(bf16x8*)(dst + k*8) = o;
    }
}

// In-place LayerNorm over rows of 768
__global__ __launch_bounds__(256) void ln_kernel(float* __restrict__ out,
        const float* __restrict__ gamma, const float* __restrict__ beta) {
    int w = threadIdx.x >> 6, u = threadIdx.x & 63;
    size_t row = (size_t)blockIdx.x * 4 + w;
    float x[12];
    float s = 0.f;
    #pragma unroll
    for (int i = 0; i < 12; i++) { x[i] = out[row*DM + i*64 + u]; s += x[i]; }
    #pragma unroll
    for (int d = 1; d < 64; d <<= 1) s += __shfl_xor(s, d);
    float mu = s * (1.0f/768.0f);
    float v = 0.f;
    #pragma unroll
    for (int i = 0; i < 12; i++) { float t = x[i] - mu; v += t*t; }
    #pragma unroll
    for (int d = 1; d < 64; d <<= 1) v += __shfl_xor(v, d);
    float rstd = rsqrtf(v * (1.0f/768.0f) + 1e-5f);
    #pragma unroll
    for (int i = 0; i < 12; i++)
        out[row*DM + i*64 + u] = (x[i] - mu) * rstd * gamma[i*64 + u] + beta[i*64 + u];
}

extern "C" void kernel_launch(void* const* d_in, const int* in_sizes, int n_in,
                              void* d_out, int out_size, void* d_ws, size_t ws_size,
                              hipStream_t stream) {
    const float* Q    = (const float*)d_in[0];
    const float* K    = (const float*)d_in[1];
    const float* V    = (const float*)d_in[2];
    const void*  mask = d_in[3];
    const float* WQ   = (const float*)d_in[4];
    const float* bQ   = (const float*)d_in[5];
    const float* WK   = (const float*)d_in[6];
    const float* bK   = (const float*)d_in[7];
    const float* WV   = (const float*)d_in[8];
    const float* bV   = (const float*)d_in[9];
    const float* Wfc  = (const float*)d_in[10];
    const float* bfc  = (const float*)d_in[11];
    const float* gam  = (const float*)d_in[12];
    const float* bet  = (const float*)d_in[13];
    float* out = (float*)d_out;
    char* ws = (char*)d_ws;

    unsigned int* maskw  = (unsigned int*)(ws + OFF_MASK);
    bf16_t* WT           = (bf16_t*)(ws + OFF_WT);
    bf16_t* XB           = (bf16_t*)(ws + OFF_XB);
    bf16_t* QP           = (bf16_t*)(ws + OFF_QP);
    bf16_t* KP           = (bf16_t*)(ws + OFF_KP);
    bf16_t* VT           = (bf16_t*)(ws + OFF_VT);
    float*  ML           = (float*)(ws + OFF_ML);
    bf16_t* CTX          = XB;                                    // alias slot 0
    bf16_t* OP           = (bf16_t*)(ws + OFF_XB + SZ_X);        // alias slots 1,2

    pack_mask_kernel<<<2048, 256, 0, stream>>>((const unsigned int*)mask, maskw);
    xcvt_kernel<<<dim3(3072, 3), 256, 0, stream>>>(Q, K, V, XB);
    wt_cvt_kernel<<<dim3(12, 12, 4), 256, 0, stream>>>(WQ, WK, WV, Wfc, WT);
    proj192_kernel<<<dim3(256, 3), 256, 0, stream>>>(XB, WT, bQ, bK, bV, QP, KP, VT);
    attn_kernel<<<dim3(SEQ/128, HEADS, BATCH*2), 256, 0, stream>>>(QP, KP, VT, maskw, OP, ML);
    attn_combine_kernel<<<dim3(SEQ/64, HEADS, BATCH), 256, 0, stream>>>(OP, ML, CTX);
    out192_kernel<<<256, 256, 0, stream>>>(CTX, WT + (size_t)3*DM*DM, bfc, Q, out);
    ln_kernel<<<2048, 256, 0, stream>>>(out, gam, bet);
}

// Round 10
// 391.454 us; speedup vs baseline: 1.0414x; 1.0414x over previous
//
#include <hip/hip_runtime.h>
#include <stdint.h>

#define DM   768
#define HEADS 12
#define DK    64
#define SEQ  2048
#define BATCH  4

typedef __bf16 bf16_t;
typedef __bf16 bf16x8 __attribute__((ext_vector_type(8)));
typedef __bf16 bf16x4 __attribute__((ext_vector_type(4)));
typedef float  f32x4  __attribute__((ext_vector_type(4)));
typedef float  f32x16 __attribute__((ext_vector_type(16)));
typedef unsigned u32x4 __attribute__((ext_vector_type(4)));

#define LOG2E 1.44269504f
#define MASKVAL (-1.442695e9f)
#define DEFER_THR 8.0f

// ---- workspace layout (bytes), all 256-aligned ----
#define OFF_MASK 256
#define SZ_MASK  (BATCH*SEQ*(SEQ/32)*4)          // 2 MB packed mask bits
#define OFF_WT   (OFF_MASK + SZ_MASK)
#define SZ_WT1   (DM*DM*2)                       // one bf16 weight (transposed)
#define OFF_XB   (OFF_WT + 4*SZ_WT1)             // bf16 Q,K,V inputs (3 x 12.6MB)
#define SZ_X     (BATCH*SEQ*DM*2)
#define OFF_QP   (OFF_XB + 3*SZ_X)
#define SZ_PROJ  (BATCH*HEADS*SEQ*DK*2)          // 12.6 MB
#define OFF_KP   (OFF_QP + SZ_PROJ)
#define OFF_VT   (OFF_KP + SZ_PROJ)
#define OFF_ML   (OFF_VT + SZ_PROJ)              // 2 x [B][H][S] x {m,l} f32
#define SZ_ML    (2*BATCH*HEADS*SEQ*2*4)
// OP (split-kv partial O) aliases XB slots 1,2; CTX aliases XB slot 0.

// prep zones
#define PREP_PACK_BLKS 2048
#define PREP_XCVT_BLKS (3072*3)
#define PREP_WT_BLKS   (12*12*4)
#define PREP_TOTAL (PREP_PACK_BLKS + PREP_XCVT_BLKS + PREP_WT_BLKS)

__device__ __forceinline__ void gload_lds16(const bf16_t* g, bf16_t* l) {
    __builtin_amdgcn_global_load_lds((const __attribute__((address_space(1))) unsigned int*)g,
                                     (__attribute__((address_space(3))) unsigned int*)l, 16, 0, 0);
}

__device__ __forceinline__ unsigned pack2(float lo, float hi) {
    union { bf16_t b[2]; unsigned u; } x;
    x.b[0] = (bf16_t)lo; x.b[1] = (bf16_t)hi;
    return x.u;
}

// Merged prep: zone 0 pack_mask, zone 1 xcvt, zone 2 wt_cvt. One launch.
__global__ void prep_kernel(const unsigned int* __restrict__ mraw, unsigned int* __restrict__ words,
                            const float* __restrict__ Q, const float* __restrict__ K,
                            const float* __restrict__ V, bf16_t* __restrict__ XB,
                            const float* __restrict__ W0, const float* __restrict__ W1,
                            const float* __restrict__ W2, const float* __restrict__ W3,
                            bf16_t* __restrict__ WT) {
    __shared__ float tile[64][65];
    int bid = blockIdx.x;
    int tid = threadIdx.x;
    if (bid < PREP_PACK_BLKS) {
        // ---- pack mask (True => masked) into bits; width detected in-kernel ----
        int is32 = 1;
        #pragma unroll
        for (int i = 0; i < 64; i++) is32 &= ((mraw[i] & 0xFFFFFF00u) == 0u);
        const unsigned int total = BATCH*SEQ*SEQ;
        const int* mi = (const int*)mraw;
        const unsigned char* mb = (const unsigned char*)mraw;
        unsigned int stride = PREP_PACK_BLKS * 256;
        unsigned int lane = tid & 63u;
        for (unsigned int e = bid * 256 + tid; e < total; e += stride) {
            int v = is32 ? (mi[e] != 0) : (mb[e] != 0);
            unsigned long long bal = __ballot(v);
            if ((lane & 31u) == 0u)
                words[e >> 5] = (unsigned int)(bal >> ((lane >> 5) * 32u));
        }
    } else if (bid < PREP_PACK_BLKS + PREP_XCVT_BLKS) {
        // ---- convert fp32 inputs to bf16 ----
        int rel = bid - PREP_PACK_BLKS;
        int z = rel / 3072, ix = rel % 3072;
        const float* src = z == 0 ? Q : z == 1 ? K : V;
        bf16_t* dst = XB + (size_t)z * BATCH*SEQ*DM;
        size_t i = ((size_t)ix * 256 + tid) * 8;
        float4 a = *(const float4*)(src + i);
        float4 b = *(const float4*)(src + i + 4);
        bf16x8 o;
        o[0]=(bf16_t)a.x; o[1]=(bf16_t)a.y; o[2]=(bf16_t)a.z; o[3]=(bf16_t)a.w;
        o[4]=(bf16_t)b.x; o[5]=(bf16_t)b.y; o[6]=(bf16_t)b.z; o[7]=(bf16_t)b.w;
        *(bf16x8*)(dst + i) = o;
    } else {
        // ---- transpose + convert weights: W[k][n] f32 -> Wt[n][k] bf16 ----
        int rel = bid - PREP_PACK_BLKS - PREP_XCVT_BLKS;
        int z = rel / 144, r2 = rel % 144;
        int bx = r2 / 12, by = r2 % 12;
        const float* W = z == 0 ? W0 : z == 1 ? W1 : z == 2 ? W2 : W3;
        bf16_t* out = WT + (size_t)z * DM * DM;
        int w = tid >> 6, u = tid & 63;
        int kb = bx * 64, nb = by * 64;
        #pragma unroll
        for (int i = 0; i < 16; i++)
            tile[w + 4*i][u] = W[(size_t)(kb + w + 4*i)*DM + nb + u];
        __syncthreads();
        #pragma unroll
        for (int i = 0; i < 16; i++)
            out[(size_t)(nb + w + 4*i)*DM + kb + u] = (bf16_t)tile[u][w + 4*i];
    }
}

// 256x96 tile mainloop (BM=256, BN=96), 4 waves as 4m x 1n
__device__ __forceinline__ void mm_mainloop256(const bf16_t* __restrict__ Aptr,
                                               const bf16_t* __restrict__ Bptr,
                                               bf16_t* As, bf16_t* Bs,
                                               f32x4 acc[4][6], int bm, int bn) {
    int tid = threadIdx.x, w = tid >> 6, u = tid & 63, c = u & 15, g = u >> 4;
    for (int k0 = 0; k0 < DM; k0 += 64) {
        #pragma unroll
        for (int i = 0; i < 8; i++) {
            int q = i*256 + tid;
            int row = q >> 3, col8 = q & 7;
            gload_lds16(Aptr + (size_t)(bm*256 + row)*DM + k0 + col8*8, As + (i*256 + w*64)*8);
        }
        #pragma unroll
        for (int i = 0; i < 3; i++) {
            int q = i*256 + tid;
            int row = q >> 3, col8 = q & 7;
            gload_lds16(Bptr + (size_t)(bn*96 + row)*DM + k0 + col8*8, Bs + (i*256 + w*64)*8);
        }
        __syncthreads();
        #pragma unroll
        for (int kk = 0; kk < 2; kk++) {
            bf16x8 a[4], bfr[6];
            #pragma unroll
            for (int mi = 0; mi < 4; mi++)
                a[mi] = *(const bf16x8*)(As + (w*64 + mi*16 + c)*64 + kk*32 + g*8);
            #pragma unroll
            for (int ni = 0; ni < 6; ni++)
                bfr[ni] = *(const bf16x8*)(Bs + (ni*16 + c)*64 + kk*32 + g*8);
            #pragma unroll
            for (int mi = 0; mi < 4; mi++)
                #pragma unroll
                for (int ni = 0; ni < 6; ni++)
                    acc[mi][ni] = __builtin_amdgcn_mfma_f32_16x16x32_bf16(a[mi], bfr[ni], acc[mi][ni], 0, 0, 0);
        }
        __syncthreads();
    }
}

// QKV projections: z=0 Q (scaled 0.125*log2e), z=1 K, z=2 V (transposed store)
__global__ __launch_bounds__(256) void proj256_kernel(
        const bf16_t* __restrict__ XB, const bf16_t* __restrict__ WT,
        const float* __restrict__ bQ, const float* __restrict__ bK, const float* __restrict__ bV,
        bf16_t* __restrict__ QP, bf16_t* __restrict__ KP, bf16_t* __restrict__ VT) {
    int z = blockIdx.z;
    const bf16_t* Aptr = XB + (size_t)z * BATCH*SEQ*DM;
    const bf16_t* Bptr = WT + (size_t)z * DM * DM;
    const float* bias = z == 0 ? bQ : z == 1 ? bK : bV;
    float scale = (z == 0) ? 0.125f * LOG2E : 1.0f;
    __shared__ __align__(16) bf16_t As[256*64], Bs[96*64];
    int tid = threadIdx.x, w = tid >> 6, u = tid & 63, c = u & 15, g = u >> 4;
    int bm = blockIdx.x, bn = blockIdx.y;
    f32x4 zero = {0.f,0.f,0.f,0.f};
    f32x4 acc[4][6] = {{zero,zero,zero,zero,zero,zero},{zero,zero,zero,zero,zero,zero},
                       {zero,zero,zero,zero,zero,zero},{zero,zero,zero,zero,zero,zero}};
    mm_mainloop256(Aptr, Bptr, As, Bs, acc, bm, bn);
    #pragma unroll
    for (int ni = 0; ni < 6; ni++) {
        int n = bn*96 + ni*16 + c;
        int h = n >> 6, d = n & 63;
        float bv = bias[n];
        if (z < 2) {
            bf16_t* dst = (z == 0) ? QP : KP;
            #pragma unroll
            for (int mi = 0; mi < 4; mi++)
                #pragma unroll
                for (int j = 0; j < 4; j++) {
                    int r = bm*256 + w*64 + mi*16 + 4*g + j;
                    int bidx = r >> 11, s = r & 2047;
                    dst[(((size_t)bidx*HEADS + h)*SEQ + s)*DK + d] = (bf16_t)((acc[mi][ni][j] + bv)*scale);
                }
        } else {
            #pragma unroll
            for (int mi = 0; mi < 4; mi++) {
                bf16x4 pk;
                #pragma unroll
                for (int j = 0; j < 4; j++) pk[j] = (bf16_t)(acc[mi][ni][j] + bv);
                int r0 = bm*256 + w*64 + mi*16 + 4*g;
                int bidx = r0 >> 11, s0 = r0 & 2047;
                *(bf16x4*)(VT + (((size_t)bidx*HEADS + h)*DK + d)*SEQ + s0) = pk;
            }
        }
    }
}

// Output projection: out = CTX @ Wfc + bfc + Q (fp32)
__global__ __launch_bounds__(256) void out256_kernel(
        const bf16_t* __restrict__ CTX, const bf16_t* __restrict__ WfcT,
        const float* __restrict__ bfc, const float* __restrict__ Qres, float* __restrict__ out) {
    __shared__ __align__(16) bf16_t As[256*64], Bs[96*64];
    int tid = threadIdx.x, w = tid >> 6, u = tid & 63, c = u & 15, g = u >> 4;
    int bm = blockIdx.x, bn = blockIdx.y;
    f32x4 zero = {0.f,0.f,0.f,0.f};
    f32x4 acc[4][6] = {{zero,zero,zero,zero,zero,zero},{zero,zero,zero,zero,zero,zero},
                       {zero,zero,zero,zero,zero,zero},{zero,zero,zero,zero,zero,zero}};
    mm_mainloop256(CTX, WfcT, As, Bs, acc, bm, bn);
    #pragma unroll
    for (int ni = 0; ni < 6; ni++) {
        int n = bn*96 + ni*16 + c;
        float bv = bfc[n];
        #pragma unroll
        for (int mi = 0; mi < 4; mi++)
            #pragma unroll
            for (int j = 0; j < 4; j++) {
                int r = bm*256 + w*64 + mi*16 + 4*g + j;
                out[(size_t)r*DM + n] = acc[mi][ni][j] + bv + Qres[(size_t)r*DM + n];
            }
    }
}

// ---------------- Flash attention, split-KV 2-way (R9-verified) ----------------
__global__ __launch_bounds__(256) void attn_kernel(
        const bf16_t* __restrict__ QP, const bf16_t* __restrict__ KP, const bf16_t* __restrict__ VT,
        const unsigned int* __restrict__ maskw, bf16_t* __restrict__ OP, float* __restrict__ ML) {
    __shared__ __align__(16) bf16_t kbuf[2][64*64];
    __shared__ __align__(16) bf16_t vbuf[2][64*64];
    __shared__ __align__(16) float lut4[64];
    int tid = threadIdx.x, w = tid >> 6, u = tid & 63;
    int qc = u & 31, hi = u >> 5;
    int sp = blockIdx.z & 1, b = blockIdx.z >> 1, h = blockIdx.y;
    int kvbase = sp << 10;
    int qg = blockIdx.x * 128 + w * 32 + qc;      // this lane's q row
    size_t bh = (size_t)(b * HEADS + h);
    const bf16_t* qp = QP + bh * SEQ * DK;
    const bf16_t* kp = KP + bh * SEQ * DK;
    const bf16_t* vt = VT + bh * DK * SEQ;
    const unsigned int* mwq = maskw + ((size_t)b * SEQ + qg) * (SEQ/32);

    // mask LUT: entry e (4 bits) -> 4 floats {0 or MASKVAL}
    if (tid < 64) lut4[tid] = (((tid >> 2) >> (tid & 3)) & 1) ? MASKVAL : 0.f;

    // persistent Q fragments (B-operand)
    bf16x8 qf[4];
    #pragma unroll
    for (int t = 0; t < 4; t++)
        qf[t] = *(const bf16x8*)(qp + (size_t)qg*DK + 16*t + 8*hi);

    int sr = tid >> 3, scc = tid & 7;

    f32x16 zz = {0,0,0,0,0,0,0,0,0,0,0,0,0,0,0,0};
    f32x16 acc0 = zz, acc1 = zz;
    float mrun = -16384.0f, lsum = 0.f;

    // prologue: stage tile 0 into buf 0
    #pragma unroll
    for (int i = 0; i < 2; i++) {
        int r = i*32 + sr;
        int gc = (scc ^ (r & 7)) << 3;
        gload_lds16(kp + (size_t)(kvbase + r)*DK + gc,   &kbuf[0][0] + i*2048 + tid*8);
        gload_lds16(vt + (size_t)r*SEQ + kvbase + gc,    &vbuf[0][0] + i*2048 + tid*8);
    }
    uint2 mv = *(const uint2*)(mwq + (kvbase >> 5));
    __syncthreads();

    for (int kt = 0; kt < 16; kt++) {
        int kb = kvbase + kt * 64;
        int cur = kt & 1;
        uint2 mv_next = mv;
        // prefetch next mask words + stage next K/V tile
        if (kt + 1 < 16) {
            mv_next = *(const uint2*)(mwq + ((kb + 64) >> 5));
            int nkb = kb + 64;
            #pragma unroll
            for (int i = 0; i < 2; i++) {
                int r = i*32 + sr;
                int gc = (scc ^ (r & 7)) << 3;
                gload_lds16(kp + (size_t)(nkb + r)*DK + gc, &kbuf[cur^1][0] + i*2048 + tid*8);
                gload_lds16(vt + (size_t)r*SEQ + nkb + gc,  &vbuf[cur^1][0] + i*2048 + tid*8);
            }
        }
        const bf16_t* kl = &kbuf[cur][0];
        const bf16_t* vl = &vbuf[cur][0];

        // mask add-values via LDS LUT -> fed directly as the MFMA C operand
        f32x16 s0, s1;
        #pragma unroll
        for (int j = 0; j < 4; j++) {
            f32x4 a0 = *(const f32x4*)&lut4[((mv.x >> (8*j + 4*hi)) & 0xFu) * 4];
            f32x4 a1 = *(const f32x4*)&lut4[((mv.y >> (8*j + 4*hi)) & 0xFu) * 4];
            #pragma unroll
            for (int i = 0; i < 4; i++) { s0[4*j + i] = a0[i]; s1[4*j + i] = a1[i]; }
        }

        // QK^T (S^T): 8 x mfma_32x32x16, accumulating onto the mask values
        __builtin_amdgcn_s_setprio(1);
        #pragma unroll
        for (int t = 0; t < 4; t++) {
            int col = (16*t + 8*hi);
            int r0 = qc, r1 = 32 + qc;
            bf16x8 k0 = *(const bf16x8*)(kl + r0*64 + (col ^ ((r0 & 7) << 3)));
            bf16x8 k1 = *(const bf16x8*)(kl + r1*64 + (col ^ ((r1 & 7) << 3)));
            s0 = __builtin_amdgcn_mfma_f32_32x32x16_bf16(k0, qf[t], s0, 0, 0, 0);
            s1 = __builtin_amdgcn_mfma_f32_32x32x16_bf16(k1, qf[t], s1, 0, 0, 0);
        }
        __builtin_amdgcn_s_setprio(0);

        // per-lane tile max, grouped 4-way for v_max3 fusion
        float q8[8];
        #pragma unroll
        for (int r = 0; r < 8; r++)
            q8[r] = fmaxf(fmaxf(s0[r], s0[r+8]), fmaxf(s1[r], s1[r+8]));
        float q4a = fmaxf(fmaxf(q8[0], q8[1]), fmaxf(q8[2], q8[3]));
        float q4b = fmaxf(fmaxf(q8[4], q8[5]), fmaxf(q8[6], q8[7]));
        float tm = fmaxf(q4a, q4b);

        // defer-max: rescale only if some row grew past mrun + THR
        if (!__all(tm <= mrun + DEFER_THR)) {
            float rmax = fmaxf(tm, __shfl_xor(tm, 32));
            float mn = fmaxf(mrun, rmax);
            float alpha = __builtin_amdgcn_exp2f(mrun - mn);
            mrun = mn;
            lsum *= alpha;
            acc0 *= alpha;
            acc1 *= alpha;
        }

        // exp2 (p bounded by 2^THR)
        #pragma unroll
        for (int r = 0; r < 16; r++) {
            s0[r] = __builtin_amdgcn_exp2f(s0[r] - mrun);
            s1[r] = __builtin_amdgcn_exp2f(s1[r] - mrun);
        }
        // sum
        f32x16 sv = s0 + s1;
        float a8[8];
        #pragma unroll
        for (int r = 0; r < 8; r++) a8[r] = sv[r] + sv[r+8];
        float a4a = (a8[0] + a8[1]) + (a8[2] + a8[3]);
        float a4b = (a8[4] + a8[5]) + (a8[6] + a8[7]);
        float rsum = a4a + a4b;
        lsum += rsum + __shfl_xor(rsum, 32);

        // P -> bf16 PA fragments via pack2 + permlane32_swap
        bf16x8 pa[4];
        {
            union { u32x4 uv; bf16x8 bv; } cv;
            unsigned x0, y0, x1, y1;
            x0 = pack2(s0[0], s0[1]); y0 = pack2(s0[4], s0[5]);
            asm volatile("v_permlane32_swap_b32 %0, %1" : "+v"(x0), "+v"(y0));
            x1 = pack2(s0[2], s0[3]); y1 = pack2(s0[6], s0[7]);
            asm volatile("v_permlane32_swap_b32 %0, %1" : "+v"(x1), "+v"(y1));
            cv.uv[0]=x0; cv.uv[1]=x1; cv.uv[2]=y0; cv.uv[3]=y1; pa[0]=cv.bv;
            x0 = pack2(s0[8], s0[9]);  y0 = pack2(s0[12], s0[13]);
            asm volatile("v_permlane32_swap_b32 %0, %1" : "+v"(x0), "+v"(y0));
            x1 = pack2(s0[10], s0[11]); y1 = pack2(s0[14], s0[15]);
            asm volatile("v_permlane32_swap_b32 %0, %1" : "+v"(x1), "+v"(y1));
            cv.uv[0]=x0; cv.uv[1]=x1; cv.uv[2]=y0; cv.uv[3]=y1; pa[1]=cv.bv;
            x0 = pack2(s1[0], s1[1]); y0 = pack2(s1[4], s1[5]);
            asm volatile("v_permlane32_swap_b32 %0, %1" : "+v"(x0), "+v"(y0));
            x1 = pack2(s1[2], s1[3]); y1 = pack2(s1[6], s1[7]);
            asm volatile("v_permlane32_swap_b32 %0, %1" : "+v"(x1), "+v"(y1));
            cv.uv[0]=x0; cv.uv[1]=x1; cv.uv[2]=y0; cv.uv[3]=y1; pa[2]=cv.bv;
            x0 = pack2(s1[8], s1[9]);  y0 = pack2(s1[12], s1[13]);
            asm volatile("v_permlane32_swap_b32 %0, %1" : "+v"(x0), "+v"(y0));
            x1 = pack2(s1[10], s1[11]); y1 = pack2(s1[14], s1[15]);
            asm volatile("v_permlane32_swap_b32 %0, %1" : "+v"(x1), "+v"(y1));
            cv.uv[0]=x0; cv.uv[1]=x1; cv.uv[2]=y0; cv.uv[3]=y1; pa[3]=cv.bv;
        }

        // PV: O^T += V^T . P^T
        __builtin_amdgcn_s_setprio(1);
        #pragma unroll
        for (int ks = 0; ks < 4; ks++) {
            int col = 16*ks + 8*hi;
            int r0 = qc, r1 = 32 + qc;
            bf16x8 v0 = *(const bf16x8*)(vl + r0*64 + (col ^ ((r0 & 7) << 3)));
            bf16x8 v1 = *(const bf16x8*)(vl + r1*64 + (col ^ ((r1 & 7) << 3)));
            acc0 = __builtin_amdgcn_mfma_f32_32x32x16_bf16(v0, pa[ks], acc0, 0, 0, 0);
            acc1 = __builtin_amdgcn_mfma_f32_32x32x16_bf16(v1, pa[ks], acc1, 0, 0, 0);
        }
        __builtin_amdgcn_s_setprio(0);

        __syncthreads();
        mv = mv_next;
    }

    // write unnormalized partial O^T (bf16) + (m,l)
    size_t prow = ((size_t)(sp * BATCH + b) * HEADS + h) * SEQ + qg;
    #pragma unroll
    for (int gr = 0; gr < 4; gr++) {
        bf16x4 o0, o1;
        #pragma unroll
        for (int jj = 0; jj < 4; jj++) {
            o0[jj] = (bf16_t)acc0[4*gr + jj];
            o1[jj] = (bf16_t)acc1[4*gr + jj];
        }
        *(bf16x4*)(OP + prow*DK + gr*8 + hi*4)      = o0;
        *(bf16x4*)(OP + prow*DK + 32 + gr*8 + hi*4) = o1;
    }
    if (hi == 0) {
        float2 ml = {mrun, lsum};
        *(float2*)(ML + prow*2) = ml;
    }
}

// Combine split-KV partials -> CTX (bf16)
__global__ __launch_bounds__(256) void attn_combine_kernel(
        const bf16_t* __restrict__ OP, const float* __restrict__ ML, bf16_t* __restrict__ CTX) {
    int tid = threadIdx.x;
    int r = tid >> 2, dc = (tid & 3) << 4;
    int h = blockIdx.y, b = blockIdx.z;
    int q = blockIdx.x * 64 + r;
    const size_t P = (size_t)BATCH * HEADS * SEQ;
    size_t row0 = ((size_t)b * HEADS + h) * SEQ + q;
    size_t row1 = row0 + P;
    float2 ml0 = *(const float2*)(ML + row0*2);
    float2 ml1 = *(const float2*)(ML + row1*2);
    float M = fmaxf(ml0.x, ml1.x);
    float w0 = exp2f(ml0.x - M), w1 = exp2f(ml1.x - M);
    float inv = 1.0f / (w0*ml0.y + w1*ml1.y);
    w0 *= inv; w1 *= inv;
    const bf16x8* pa = (const bf16x8*)(OP + row0*DK + dc);
    const bf16x8* pb = (const bf16x8*)(OP + row1*DK + dc);
    bf16_t* dst = CTX + ((size_t)b*SEQ + q)*DM + h*DK + dc;
    #pragma unroll
    for (int k = 0; k < 2; k++) {
        bf16x8 av = pa[k], bv = pb[k];
        bf16x8 o;
        #pragma unroll
        for (int i = 0; i < 8; i++)
            o[i] = (bf16_t)((float)av[i]*w0 + (float)bv[i]*w1);
        *(bf16x8*)(dst + k*8) = o;
    }
}

// In-place LayerNorm over rows of 768
__global__ __launch_bounds__(256) void ln_kernel(float* __restrict__ out,
        const float* __restrict__ gamma, const float* __restrict__ beta) {
    int w = threadIdx.x >> 6, u = threadIdx.x & 63;
    size_t row = (size_t)blockIdx.x * 4 + w;
    float x[12];
    float s = 0.f;
    #pragma unroll
    for (int i = 0; i < 12; i++) { x[i] = out[row*DM + i*64 + u]; s += x[i]; }
    #pragma unroll
    for (int d = 1; d < 64; d <<= 1) s += __shfl_xor(s, d);
    float mu = s * (1.0f/768.0f);
    float v = 0.f;
    #pragma unroll
    for (int i = 0; i < 12; i++) { float t = x[i] - mu; v += t*t; }
    #pragma unroll
    for (int d = 1; d < 64; d <<= 1) v += __shfl_xor(v, d);
    float rstd = rsqrtf(v * (1.0f/768.0f) + 1e-5f);
    #pragma unroll
    for (int i = 0; i < 12; i++)
        out[row*DM + i*64 + u] = (x[i] - mu) * rstd * gamma[i*64 + u] + beta[i*64 + u];
}

extern "C" void kernel_launch(void* const* d_in, const int* in_sizes, int n_in,
                              void* d_out, int out_size, void* d_ws, size_t ws_size,
                              hipStream_t stream) {
    const float* Q    = (const float*)d_in[0];
    const float* K    = (const float*)d_in[1];
    const float* V    = (const float*)d_in[2];
    const void*  mask = d_in[3];
    const float* WQ   = (const float*)d_in[4];
    const float* bQ   = (const float*)d_in[5];
    const float* WK   = (const float*)d_in[6];
    const float* bK   = (const float*)d_in[7];
    const float* WV   = (const float*)d_in[8];
    const float* bV   = (const float*)d_in[9];
    const float* Wfc  = (const float*)d_in[10];
    const float* bfc  = (const float*)d_in[11];
    const float* gam  = (const float*)d_in[12];
    const float* bet  = (const float*)d_in[13];
    float* out = (float*)d_out;
    char* ws = (char*)d_ws;

    unsigned int* maskw  = (unsigned int*)(ws + OFF_MASK);
    bf16_t* WT           = (bf16_t*)(ws + OFF_WT);
    bf16_t* XB           = (bf16_t*)(ws + OFF_XB);
    bf16_t* QP           = (bf16_t*)(ws + OFF_QP);
    bf16_t* KP           = (bf16_t*)(ws + OFF_KP);
    bf16_t* VT           = (bf16_t*)(ws + OFF_VT);
    float*  ML           = (float*)(ws + OFF_ML);
    bf16_t* CTX          = XB;                                    // alias slot 0
    bf16_t* OP           = (bf16_t*)(ws + OFF_XB + SZ_X);        // alias slots 1,2

    prep_kernel<<<PREP_TOTAL, 256, 0, stream>>>((const unsigned int*)mask, maskw,
                                                Q, K, V, XB, WQ, WK, WV, Wfc, WT);
    proj256_kernel<<<dim3(32, 8, 3), 256, 0, stream>>>(XB, WT, bQ, bK, bV, QP, KP, VT);
    attn_kernel<<<dim3(SEQ/128, HEADS, BATCH*2), 256, 0, stream>>>(QP, KP, VT, maskw, OP, ML);
    attn_combine_kernel<<<dim3(SEQ/64, HEADS, BATCH), 256, 0, stream>>>(OP, ML, CTX);
    out256_kernel<<<dim3(32, 8), 256, 0, stream>>>(CTX, WT + (size_t)3*DM*DM, bfc, Q, out);
    ln_kernel<<<2048, 256, 0, stream>>>(out, gam, bet);
}